// Round 10
// baseline (85.289 us; speedup 1.0000x reference)
//
#include <hip/hip_runtime.h>

// IDST (DST-III, x2) via four-step FFT (8192 = 32 x 32 x 8), one row per
// 256-thread block. R10 vs R9:
//  - twiddle factors + epilogue t_k from precomputed tables in d_ws
//    (double-precision generated once per launch) -> kills the two serial
//    32-step rotation chains, 2x __sincosf, and per-output t_k math.
//  - LDS planes merged into interleaved float2 -> DS op count halved (b64).
// Tables (float2 units in d_ws):
//   [0,8192)     TW1[k1*256+j] = exp(+i*2pi*j*k1/8192)
//   [8192,8448)  TW2[m1*8+c2]  = exp(+i*2pi*c2*m1/256)
//   [8448,12544) T3[k]         = 2*exp(+i*pi*(2k+1)/8192)   ( = 2*t_k )

#define NN 4096

__device__ static constexpr float TW32R[16] = {
    1.0f, 0.98078528f, 0.92387953f, 0.83146961f,
    0.70710678f, 0.55557023f, 0.38268343f, 0.19509032f,
    0.0f, -0.19509032f, -0.38268343f, -0.55557023f,
    -0.70710678f, -0.83146961f, -0.92387953f, -0.98078528f};
__device__ static constexpr float TW32I[16] = {
    0.0f, 0.19509032f, 0.38268343f, 0.55557023f,
    0.70710678f, 0.83146961f, 0.92387953f, 0.98078528f,
    1.0f, 0.98078528f, 0.92387953f, 0.83146961f,
    0.70710678f, 0.55557023f, 0.38268343f, 0.19509032f};
// w8^t = exp(+j*2*pi*t/8)
__device__ static constexpr float W8R[8] = {
    1.0f, 0.70710678f, 0.0f, -0.70710678f, -1.0f, -0.70710678f, 0.0f, 0.70710678f};
__device__ static constexpr float W8I[8] = {
    0.0f, 0.70710678f, 1.0f, 0.70710678f, 0.0f, -0.70710678f, -1.0f, -0.70710678f};

__device__ __forceinline__ constexpr int brev5(int x) {
    return ((x & 1) << 4) | ((x & 2) << 2) | (x & 4) | ((x & 8) >> 2) | ((x & 16) >> 4);
}

// In-register 32-point DFT, sign +1 (inverse-FFT kernel), DIF.
// Output: X[k] sits at a[brev5(k)].
__device__ __forceinline__ void fft32(float (&re)[32], float (&im)[32]) {
#pragma unroll
    for (int len = 32; len >= 2; len >>= 1) {
        const int half = len >> 1;
#pragma unroll
        for (int base = 0; base < 32; base += len) {
#pragma unroll
            for (int o = 0; o < half; ++o) {
                const int tw = o * (32 / len);
                float ur = re[base + o], ui = im[base + o];
                float vr = re[base + o + half], vi = im[base + o + half];
                re[base + o] = ur + vr;
                im[base + o] = ui + vi;
                float dr = ur - vr, di = ui - vi;
                re[base + o + half] = dr * TW32R[tw] - di * TW32I[tw];
                im[base + o + half] = dr * TW32I[tw] + di * TW32R[tw];
            }
        }
    }
}

__global__ __launch_bounds__(256) void gen_tables(float2* __restrict__ T) {
    int i = blockIdx.x * 256 + threadIdx.x;
    if (i < 8192) {
        int k1 = i >> 8, j = i & 255;
        double ang = (double)((j * k1) & 8191) * (6.283185307179586 / 8192.0);
        T[i] = make_float2((float)cos(ang), (float)sin(ang));
    } else if (i < 8448) {
        int t = i - 8192;
        int m1 = t >> 3, c2 = t & 7;
        double ang = (double)((c2 * m1) & 255) * (6.283185307179586 / 256.0);
        T[i] = make_float2((float)cos(ang), (float)sin(ang));
    } else if (i < 12544) {
        int k = i - 8448;
        double ang = (double)(2 * k + 1) * (3.141592653589793 / 8192.0);
        T[i] = make_float2(2.0f * (float)cos(ang), 2.0f * (float)sin(ang));
    }
}

__global__ __launch_bounds__(256) void idst_fft(const float* __restrict__ x,
                                                const float2* __restrict__ expk,
                                                const float2* __restrict__ T,
                                                float* __restrict__ y) {
    __shared__ float2 L[8224];   // stage1: [k1*257+c]; stage2: [k1+32*(m1*8+c2)]

    const int j = threadIdx.x;
    const int row = blockIdx.x;
    const float* xr = x + (size_t)row * NN;

    float cre[32], cim[32];

    // ---- Stage 1: b_n = a_n*x_n*e_n at n = 256*i + j (i>=16 -> zero pad) ----
#pragma unroll
    for (int i = 0; i < 16; ++i) {
        int n = j + 256 * i;
        float v = xr[n];
        if (n == NN - 1) v *= 0.5f;
        float2 e = expk[n];               // e_n = e.x + j*(-e.y)
        cre[i] = v * e.x;
        cim[i] = -v * e.y;
    }
#pragma unroll
    for (int i = 16; i < 32; ++i) { cre[i] = 0.0f; cim[i] = 0.0f; }

    fft32(cre, cim);

    // twiddle from TW1 table; write Y[k1][j]
    {
        const float2* tw1 = T + j;
#pragma unroll
        for (int k1 = 0; k1 < 32; ++k1) {
            const int s = brev5(k1);
            float2 t = tw1[k1 * 256];
            L[k1 * 257 + j] = make_float2(cre[s] * t.x - cim[s] * t.y,
                                          cre[s] * t.y + cim[s] * t.x);
        }
    }
    __syncthreads();

    // ---- Stage 2: (k1, c2) does DFT-32 over c1 of Y[k1][8*c1 + c2] ----
    const int k1 = j & 31;
    const int c2 = j >> 5;
#pragma unroll
    for (int c1 = 0; c1 < 32; ++c1) {
        float2 v = L[k1 * 257 + 8 * c1 + c2];
        cre[c1] = v.x;
        cim[c1] = v.y;
    }
    __syncthreads();   // all reads done before overwriting the buffer

    fft32(cre, cim);

    {
        const float2* tw2 = T + 8192 + c2;
#pragma unroll
        for (int m1 = 0; m1 < 32; ++m1) {
            const int s = brev5(m1);
            float2 t = tw2[m1 * 8];
            L[k1 + 32 * (m1 * 8 + c2)] = make_float2(cre[s] * t.x - cim[s] * t.y,
                                                     cre[s] * t.y + cim[s] * t.x);
        }
    }
    __syncthreads();

    // ---- Stage 3: direct DFT-8 over c2 (only m2<4 needed) + epilogue ----
    const float2* T3 = T + 8448;
    float* yr = y + (size_t)row * NN;

#pragma unroll
    for (int q = 0; q < 4; ++q) {
        const int m1 = (j >> 5) * 4 + q;
        float wre[8], wim[8];
#pragma unroll
        for (int c = 0; c < 8; ++c) {
            float2 v = L[k1 + 32 * (m1 * 8 + c)];
            wre[c] = v.x;
            wim[c] = v.y;
        }
#pragma unroll
        for (int m2 = 0; m2 < 4; ++m2) {
            float sr = 0.0f, si = 0.0f;
#pragma unroll
            for (int c = 0; c < 8; ++c) {
                const int t8 = (c * m2) & 7;
                sr += wre[c] * W8R[t8] - wim[c] * W8I[t8];
                si += wre[c] * W8I[t8] + wim[c] * W8R[t8];
            }
            const int k = k1 + 32 * m1 + 1024 * m2;
            float2 t = T3[k];                       // 2*t_k
            yr[k] = t.x * si + t.y * sr;            // 2*Im(t_k * S_k)
        }
    }
}

extern "C" void kernel_launch(void* const* d_in, const int* in_sizes, int n_in,
                              void* d_out, int out_size, void* d_ws, size_t ws_size,
                              hipStream_t stream) {
    const float*  x    = (const float*)d_in[0];
    const float2* expk = (const float2*)d_in[1];
    float* out = (float*)d_out;
    float2* T = (float2*)d_ws;

    gen_tables<<<49, 256, 0, stream>>>(T);
    idst_fft<<<NN, 256, 0, stream>>>(x, expk, T, out);
}

// Round 11
// 56.106 us; speedup vs baseline: 1.5202x; 1.5202x over previous
//
#include <hip/hip_runtime.h>

// IDST (DST-III, x2) via four-step FFT (8192 = 32 x 32 x 8), one row per
// 256-thread block. R11 = R9 (in-register sincosf twiddles — R10's global
// tables regressed at low occupancy) + two changes:
//  1) LDS halved to one 32.9 KB f32 plane, time-multiplexed:
//     transpose-1 = re pass + im pass (all threads active both passes);
//     transpose-2 = m1-halves (both planes fit), stage-3 per half.
//     -> 4 blocks/CU (was 2). __launch_bounds__(256,4) caps VGPR at 128.
//  2) stage-3 DFT-8 via even/odd DFT-4 split (radix-2): ~half the ops of
//     the direct 8x4 evaluation.

#define NN 4096

__device__ static constexpr float TW32R[16] = {
    1.0f, 0.98078528f, 0.92387953f, 0.83146961f,
    0.70710678f, 0.55557023f, 0.38268343f, 0.19509032f,
    0.0f, -0.19509032f, -0.38268343f, -0.55557023f,
    -0.70710678f, -0.83146961f, -0.92387953f, -0.98078528f};
__device__ static constexpr float TW32I[16] = {
    0.0f, 0.19509032f, 0.38268343f, 0.55557023f,
    0.70710678f, 0.83146961f, 0.92387953f, 0.98078528f,
    1.0f, 0.98078528f, 0.92387953f, 0.83146961f,
    0.70710678f, 0.55557023f, 0.38268343f, 0.19509032f};

__device__ __forceinline__ constexpr int brev5(int x) {
    return ((x & 1) << 4) | ((x & 2) << 2) | (x & 4) | ((x & 8) >> 2) | ((x & 16) >> 4);
}

// In-register 32-point DFT, sign +1 (inverse-FFT kernel), DIF.
// Output: X[k] sits at a[brev5(k)].
__device__ __forceinline__ void fft32(float (&re)[32], float (&im)[32]) {
#pragma unroll
    for (int len = 32; len >= 2; len >>= 1) {
        const int half = len >> 1;
#pragma unroll
        for (int base = 0; base < 32; base += len) {
#pragma unroll
            for (int o = 0; o < half; ++o) {
                const int tw = o * (32 / len);
                float ur = re[base + o], ui = im[base + o];
                float vr = re[base + o + half], vi = im[base + o + half];
                re[base + o] = ur + vr;
                im[base + o] = ui + vi;
                float dr = ur - vr, di = ui - vi;
                re[base + o + half] = dr * TW32R[tw] - di * TW32I[tw];
                im[base + o + half] = dr * TW32I[tw] + di * TW32R[tw];
            }
        }
    }
}

__global__ __launch_bounds__(256, 4) void idst_fft(const float* __restrict__ x,
                                                   const float2* __restrict__ expk,
                                                   float* __restrict__ y) {
    __shared__ float L[8224];   // ONE 32.9 KB plane, time-multiplexed

    const int j = threadIdx.x;
    const int row = blockIdx.x;
    const float* xr = x + (size_t)row * NN;

    float cre[32], cim[32];

    // ---- Stage 1: b_n = a_n*x_n*e_n at n = 256*i + j (i>=16 -> zero pad) ----
#pragma unroll
    for (int i = 0; i < 16; ++i) {
        int n = j + 256 * i;
        float v = xr[n];
        if (n == NN - 1) v *= 0.5f;
        float2 e = expk[n];               // e_n = e.x + j*(-e.y)
        cre[i] = v * e.x;
        cim[i] = -v * e.y;
    }
#pragma unroll
    for (int i = 16; i < 32; ++i) { cre[i] = 0.0f; cim[i] = 0.0f; }

    fft32(cre, cim);

    // ---- Transpose 1, pass A (re): write twiddled re, gather rows ----
    {
        float ss, sc;
        __sincosf((float)j * 7.66990393943e-4f, &ss, &sc);   // 2*pi/8192
        float tr = 1.0f, ti = 0.0f;
#pragma unroll
        for (int k = 0; k < 32; ++k) {
            const int s = brev5(k);
            L[k * 257 + j] = cre[s] * tr - cim[s] * ti;
            float nr = tr * sc - ti * ss;
            ti = tr * ss + ti * sc;
            tr = nr;
        }
    }
    __syncthreads();
    const int k1 = j & 31;
    const int c2 = j >> 5;
    float dre[32], dim2[32];
#pragma unroll
    for (int c1 = 0; c1 < 32; ++c1) dre[c1] = L[k1 * 257 + 8 * c1 + c2];
    __syncthreads();

    // ---- Transpose 1, pass B (im) ----
    {
        float ss, sc;
        __sincosf((float)j * 7.66990393943e-4f, &ss, &sc);
        float tr = 1.0f, ti = 0.0f;
#pragma unroll
        for (int k = 0; k < 32; ++k) {
            const int s = brev5(k);
            L[k * 257 + j] = cre[s] * ti + cim[s] * tr;
            float nr = tr * sc - ti * ss;
            ti = tr * ss + ti * sc;
            tr = nr;
        }
    }
    __syncthreads();
#pragma unroll
    for (int c1 = 0; c1 < 32; ++c1) dim2[c1] = L[k1 * 257 + 8 * c1 + c2];
    __syncthreads();   // buffer free for transpose 2

    fft32(dre, dim2);

    // ---- Transpose 2 + stage 3, in two m1-halves (both planes fit) ----
    const float2 e1 = expk[1];
    const float e1r = e1.x, e1i = -e1.y;
    float* yr = y + (size_t)row * NN;
    const float R2 = 0.70710678f;

    float ss2, sc2;
    __sincosf((float)c2 * 2.45436926062e-2f, &ss2, &sc2);    // 2*pi/256
    float tr2 = 1.0f, ti2 = 0.0f;

#pragma unroll
    for (int half = 0; half < 2; ++half) {
        const int mbase = half * 16;
        // write rows m1 = mbase..mbase+15 (re at 0, im at +4096)
#pragma unroll
        for (int ml = 0; ml < 16; ++ml) {
            const int s = brev5(mbase + ml);
            const int a = k1 + 32 * (ml * 8 + c2);
            L[a]        = dre[s] * tr2 - dim2[s] * ti2;
            L[4096 + a] = dre[s] * ti2 + dim2[s] * tr2;
            float nr = tr2 * sc2 - ti2 * ss2;
            ti2 = tr2 * ss2 + ti2 * sc2;
            tr2 = nr;
        }
        __syncthreads();
        // readers: waves whose m1 = (j>>5)*4+q fall in this half
        if ((j >> 7) == half) {
            const int h = (j >> 5) & 3;
#pragma unroll
            for (int q = 0; q < 4; ++q) {
                const int ml = h * 4 + q;
                const int m1 = mbase + ml;
                float wre[8], wim[8];
#pragma unroll
                for (int c = 0; c < 8; ++c) {
                    wre[c] = L[k1 + 32 * (ml * 8 + c)];
                    wim[c] = L[4096 + k1 + 32 * (ml * 8 + c)];
                }
                // DFT-8 (sign +), outputs m2=0..3 via even/odd DFT-4 split
                float t0r = wre[0] + wre[4], t0i = wim[0] + wim[4];
                float t1r = wre[0] - wre[4], t1i = wim[0] - wim[4];
                float t2r = wre[2] + wre[6], t2i = wim[2] + wim[6];
                float t3r = wre[2] - wre[6], t3i = wim[2] - wim[6];
                float E0r = t0r + t2r, E0i = t0i + t2i;
                float E2r = t0r - t2r, E2i = t0i - t2i;
                float E1r = t1r - t3i, E1i = t1i + t3r;
                float E3r = t1r + t3i, E3i = t1i - t3r;
                float u0r = wre[1] + wre[5], u0i = wim[1] + wim[5];
                float u1r = wre[1] - wre[5], u1i = wim[1] - wim[5];
                float u2r = wre[3] + wre[7], u2i = wim[3] + wim[7];
                float u3r = wre[3] - wre[7], u3i = wim[3] - wim[7];
                float O0r = u0r + u2r, O0i = u0i + u2i;
                float O2r = u0r - u2r, O2i = u0i - u2i;
                float O1r = u1r - u3i, O1i = u1i + u3r;
                float O3r = u1r + u3i, O3i = u1i - u3r;

                float sr[4], si[4];
                sr[0] = E0r + O0r;                  si[0] = E0i + O0i;
                sr[1] = E1r + R2 * (O1r - O1i);     si[1] = E1i + R2 * (O1r + O1i);
                sr[2] = E2r - O2i;                  si[2] = E2i + O2r;
                sr[3] = E3r - R2 * (O3r + O3i);     si[3] = E3i + R2 * (O3r - O3i);

#pragma unroll
                for (int m2 = 0; m2 < 4; ++m2) {
                    const int k = k1 + 32 * m1 + 1024 * m2;
                    float2 ek = expk[k];
                    const float er = ek.x, ei = -ek.y;     // e_k
                    const float t2r_ = er * er - ei * ei;  // e_k^2
                    const float t2i_ = 2.0f * er * ei;
                    const float tkr = t2r_ * e1r - t2i_ * e1i;  // t_k
                    const float tki = t2r_ * e1i + t2i_ * e1r;
                    yr[k] = 2.0f * (tkr * si[m2] + tki * sr[m2]);
                }
            }
        }
        __syncthreads();
    }
}

extern "C" void kernel_launch(void* const* d_in, const int* in_sizes, int n_in,
                              void* d_out, int out_size, void* d_ws, size_t ws_size,
                              hipStream_t stream) {
    const float*  x    = (const float*)d_in[0];
    const float2* expk = (const float2*)d_in[1];
    float* out = (float*)d_out;

    idst_fft<<<NN, 256, 0, stream>>>(x, expk, out);
}

// Round 12
// 39.583 us; speedup vs baseline: 2.1547x; 1.4174x over previous
//
#include <hip/hip_runtime.h>

// IDST (DST-III, x2) via four-step FFT (8192 = 32 x 32 x 8).
// R12: REAL-ROW PAIRING — one block transforms TWO rows as z = x_a + j*x_b
// (the map x -> S is complex-linear; for real rows S[8191-k] = conj(S[k])).
//   S_a[k] = (S_z[k] + conj(S_z[k']))/2,  S_b[k] = -j(S_z[k] - conj(S_z[k']))/2,
//   k' = 8191-k;  u = t_k S_z[k], v = t_k conj(S_z[k']):
//   y_a[k] = Im(u)+Im(v),  y_b[k] = Re(v)-Re(u).
// Stages 1-2 (+transposes) run once per 2 rows (~halved VALU); stage 3 does
// the full DFT-8 (8 outputs) with ALL threads active (was 50% idle), then a
// 32 KB LDS exchange delivers conj partners. Grid = 2048 blocks.

#define NN 4096

__device__ static constexpr float TW32R[16] = {
    1.0f, 0.98078528f, 0.92387953f, 0.83146961f,
    0.70710678f, 0.55557023f, 0.38268343f, 0.19509032f,
    0.0f, -0.19509032f, -0.38268343f, -0.55557023f,
    -0.70710678f, -0.83146961f, -0.92387953f, -0.98078528f};
__device__ static constexpr float TW32I[16] = {
    0.0f, 0.19509032f, 0.38268343f, 0.55557023f,
    0.70710678f, 0.83146961f, 0.92387953f, 0.98078528f,
    1.0f, 0.98078528f, 0.92387953f, 0.83146961f,
    0.70710678f, 0.55557023f, 0.38268343f, 0.19509032f};

__device__ __forceinline__ constexpr int brev5(int x) {
    return ((x & 1) << 4) | ((x & 2) << 2) | (x & 4) | ((x & 8) >> 2) | ((x & 16) >> 4);
}

// In-register 32-point DFT, sign +1 (inverse-FFT kernel), DIF.
// Output: X[k] sits at a[brev5(k)].
__device__ __forceinline__ void fft32(float (&re)[32], float (&im)[32]) {
#pragma unroll
    for (int len = 32; len >= 2; len >>= 1) {
        const int half = len >> 1;
#pragma unroll
        for (int base = 0; base < 32; base += len) {
#pragma unroll
            for (int o = 0; o < half; ++o) {
                const int tw = o * (32 / len);
                float ur = re[base + o], ui = im[base + o];
                float vr = re[base + o + half], vi = im[base + o + half];
                re[base + o] = ur + vr;
                im[base + o] = ui + vi;
                float dr = ur - vr, di = ui - vi;
                re[base + o + half] = dr * TW32R[tw] - di * TW32I[tw];
                im[base + o + half] = dr * TW32I[tw] + di * TW32R[tw];
            }
        }
    }
}

__global__ __launch_bounds__(256, 4) void idst_fft(const float* __restrict__ x,
                                                   const float2* __restrict__ expk,
                                                   float* __restrict__ y) {
    __shared__ float L[8224];   // one 32.9 KB plane, time-multiplexed

    const int j = threadIdx.x;
    const int blk = blockIdx.x;
    const float* xa = x + (size_t)(2 * blk) * NN;
    const float* xb = xa + NN;

    float cre[32], cim[32];

    // ---- Stage 1: b_n = a_n*(xa_n + j*xb_n)*e_n, n = 256*i + j; pad ----
#pragma unroll
    for (int i = 0; i < 16; ++i) {
        int n = j + 256 * i;
        float va = xa[n], vb = xb[n];
        if (n == NN - 1) { va *= 0.5f; vb *= 0.5f; }
        float2 e = expk[n];               // e_n = e.x + j*(-e.y)
        cre[i] = va * e.x + vb * e.y;
        cim[i] = vb * e.x - va * e.y;
    }
#pragma unroll
    for (int i = 16; i < 32; ++i) { cre[i] = 0.0f; cim[i] = 0.0f; }

    fft32(cre, cim);

    // ---- Transpose 1, pass A (re) ----
    {
        float ss, sc;
        __sincosf((float)j * 7.66990393943e-4f, &ss, &sc);   // 2*pi/8192
        float tr = 1.0f, ti = 0.0f;
#pragma unroll
        for (int k = 0; k < 32; ++k) {
            const int s = brev5(k);
            L[k * 257 + j] = cre[s] * tr - cim[s] * ti;
            float nr = tr * sc - ti * ss;
            ti = tr * ss + ti * sc;
            tr = nr;
        }
    }
    __syncthreads();
    const int k1 = j & 31;
    const int c2 = j >> 5;
    float dre[32], dim2[32];
#pragma unroll
    for (int c1 = 0; c1 < 32; ++c1) dre[c1] = L[k1 * 257 + 8 * c1 + c2];
    __syncthreads();

    // ---- Transpose 1, pass B (im) ----
    {
        float ss, sc;
        __sincosf((float)j * 7.66990393943e-4f, &ss, &sc);
        float tr = 1.0f, ti = 0.0f;
#pragma unroll
        for (int k = 0; k < 32; ++k) {
            const int s = brev5(k);
            L[k * 257 + j] = cre[s] * ti + cim[s] * tr;
            float nr = tr * sc - ti * ss;
            ti = tr * ss + ti * sc;
            tr = nr;
        }
    }
    __syncthreads();
#pragma unroll
    for (int c1 = 0; c1 < 32; ++c1) dim2[c1] = L[k1 * 257 + 8 * c1 + c2];
    __syncthreads();   // plane free for transpose 2

    fft32(dre, dim2);

    // ---- Transpose 2 + full DFT-8 per (k1, m1), two m1-halves ----
    const float R2 = 0.70710678f;
    float sr[4][8], si[4][8];     // [p = h*2+q][m2]  (all static indexing)

    float ss2, sc2;
    __sincosf((float)c2 * 2.45436926062e-2f, &ss2, &sc2);    // 2*pi/256
    float tr2 = 1.0f, ti2 = 0.0f;

#pragma unroll
    for (int h = 0; h < 2; ++h) {
        // write rows m1 = 16h .. 16h+15 (re at 0, im at +4096)
#pragma unroll
        for (int ml = 0; ml < 16; ++ml) {
            const int s = brev5(h * 16 + ml);
            const int a = k1 + 32 * (ml * 8 + c2);
            L[a]        = dre[s] * tr2 - dim2[s] * ti2;
            L[4096 + a] = dre[s] * ti2 + dim2[s] * tr2;
            float nr = tr2 * sc2 - ti2 * ss2;
            ti2 = tr2 * ss2 + ti2 * sc2;
            tr2 = nr;
        }
        __syncthreads();
        // all threads: DFT-8 for m1 = 16h + (j>>5)*2 + q, q = 0,1
#pragma unroll
        for (int q = 0; q < 2; ++q) {
            const int p = h * 2 + q;
            const int ml = c2 * 2 + q;
            float wre[8], wim[8];
#pragma unroll
            for (int c = 0; c < 8; ++c) {
                wre[c] = L[k1 + 32 * (ml * 8 + c)];
                wim[c] = L[4096 + k1 + 32 * (ml * 8 + c)];
            }
            float t0r = wre[0] + wre[4], t0i = wim[0] + wim[4];
            float t1r = wre[0] - wre[4], t1i = wim[0] - wim[4];
            float t2r = wre[2] + wre[6], t2i = wim[2] + wim[6];
            float t3r = wre[2] - wre[6], t3i = wim[2] - wim[6];
            float E0r = t0r + t2r, E0i = t0i + t2i;
            float E2r = t0r - t2r, E2i = t0i - t2i;
            float E1r = t1r - t3i, E1i = t1i + t3r;
            float E3r = t1r + t3i, E3i = t1i - t3r;
            float u0r = wre[1] + wre[5], u0i = wim[1] + wim[5];
            float u1r = wre[1] - wre[5], u1i = wim[1] - wim[5];
            float u2r = wre[3] + wre[7], u2i = wim[3] + wim[7];
            float u3r = wre[3] - wre[7], u3i = wim[3] - wim[7];
            float O0r = u0r + u2r, O0i = u0i + u2i;
            float O2r = u0r - u2r, O2i = u0i - u2i;
            float O1r = u1r - u3i, O1i = u1i + u3r;
            float O3r = u1r + u3i, O3i = u1i - u3r;
            // g = w8^m2 * O
            float g1r = R2 * (O1r - O1i), g1i = R2 * (O1r + O1i);
            float g2r = -O2i,             g2i = O2r;
            float g3r = -R2 * (O3r + O3i), g3i = R2 * (O3r - O3i);

            sr[p][0] = E0r + O0r;  si[p][0] = E0i + O0i;
            sr[p][1] = E1r + g1r;  si[p][1] = E1i + g1i;
            sr[p][2] = E2r + g2r;  si[p][2] = E2i + g2i;
            sr[p][3] = E3r + g3r;  si[p][3] = E3i + g3i;
            sr[p][4] = E0r - O0r;  si[p][4] = E0i - O0i;
            sr[p][5] = E1r - g1r;  si[p][5] = E1i - g1i;
            sr[p][6] = E2r - g2r;  si[p][6] = E2i - g2i;
            sr[p][7] = E3r - g3r;  si[p][7] = E3i - g3i;
        }
        __syncthreads();
    }

    // ---- Exchange: publish S_z[k] for k in [4096,8192) at L[2(k-4096)] ----
#pragma unroll
    for (int p = 0; p < 4; ++p) {
        const int m1 = (p >> 1) * 16 + c2 * 2 + (p & 1);
#pragma unroll
        for (int m2 = 4; m2 < 8; ++m2) {
            const int off = 2 * k1 + 64 * m1 + 2048 * m2 - 8192;
            L[off]     = sr[p][m2];
            L[off + 1] = si[p][m2];
        }
    }
    __syncthreads();

    // ---- Combine with conj partner + epilogue; write both rows ----
    const float2 e1v = expk[1];
    const float e1r = e1v.x, e1i = -e1v.y;
    float* ya = y + (size_t)(2 * blk) * NN;
    float* yb = ya + NN;

#pragma unroll
    for (int p = 0; p < 4; ++p) {
        const int m1 = (p >> 1) * 16 + c2 * 2 + (p & 1);
#pragma unroll
        for (int m2 = 0; m2 < 4; ++m2) {
            const int k = k1 + 32 * m1 + 1024 * m2;
            const int off = 8190 - 2 * k;          // partner k' = 8191-k
            const float pvr = L[off], pvi = L[off + 1];
            float2 ek = expk[k];
            const float er = ek.x, ei = -ek.y;     // e_k
            const float q2r = er * er - ei * ei;   // e_k^2
            const float q2i = 2.0f * er * ei;
            const float tkr = q2r * e1r - q2i * e1i;   // t_k = e_k^2 * e_1
            const float tki = q2r * e1i + q2i * e1r;
            const float urr = tkr * sr[p][m2] - tki * si[p][m2];  // u = t*Sz[k]
            const float uii = tkr * si[p][m2] + tki * sr[p][m2];
            const float vrr = tkr * pvr + tki * pvi;   // v = t*conj(Sz[k'])
            const float vii = tki * pvr - tkr * pvi;
            ya[k] = uii + vii;
            yb[k] = vrr - urr;
        }
    }
}

extern "C" void kernel_launch(void* const* d_in, const int* in_sizes, int n_in,
                              void* d_out, int out_size, void* d_ws, size_t ws_size,
                              hipStream_t stream) {
    const float*  x    = (const float*)d_in[0];
    const float2* expk = (const float2*)d_in[1];
    float* out = (float*)d_out;

    idst_fft<<<NN / 2, 256, 0, stream>>>(x, expk, out);
}